// Round 1
// baseline (408.242 us; speedup 1.0000x reference)
//
#include <hip/hip_runtime.h>

// One thread per batch column. Upper-bound binary search over the sorted
// column times[:, b] (time-major layout, row stride = nbatch floats).
// Key trick: the final lo of an upper-bound search was always set by a
// success at mid == lo-1, and the final hi by a failure at mid == lo, so
// times[lo-1] and times[lo] are captured in registers during the search —
// the epilogue only needs the two values[] gathers.
__global__ void bts_interp_kernel(const float* __restrict__ times,
                                  const float* __restrict__ values,
                                  const float* __restrict__ t,
                                  float* __restrict__ out,
                                  int ntime, int nbatch) {
    int b = blockIdx.x * blockDim.x + threadIdx.x;
    if (b >= nbatch) return;

    float tq = t[b];

    int lo = 0, hi = ntime;
    float t0v = 0.0f;  // times[lo-1] once lo > 0
    float t1v = 0.0f;  // times[lo]   once hi < ntime
    while (lo < hi) {
        int mid = (lo + hi) >> 1;
        float v = times[(long)mid * nbatch + b];
        if (v <= tq) { lo = mid + 1; t0v = v; }
        else         { hi = mid;     t1v = v; }
    }
    // lo == count of times <= tq, in [0, ntime]. gi = lo mod ntime.

    float res;
    if (lo > 0 && lo < ntime) {
        // normal case: iv = isl = lo-1; t0 = times[lo-1] = t0v, t1 = times[lo] = t1v
        long base = (long)(lo - 1) * nbatch + b;
        float va = values[base];
        float vb = values[base + nbatch];
        res = va + (vb - va) / (t1v - t0v) * (tq - t0v);
    } else {
        // gi == 0 (t below all knots, or >= all knots): iv = ntime-1, isl = ntime-2
        long base = (long)(ntime - 2) * nbatch + b;
        float ta = times[base];
        float tb = times[base + nbatch];
        float va = values[base];
        float vb = values[base + nbatch];
        res = vb + (vb - va) / (tb - ta) * (tq - tb);
    }
    out[b] = res;
}

extern "C" void kernel_launch(void* const* d_in, const int* in_sizes, int n_in,
                              void* d_out, int out_size, void* d_ws, size_t ws_size,
                              hipStream_t stream) {
    const float* times  = (const float*)d_in[0];
    const float* values = (const float*)d_in[1];
    const float* t      = (const float*)d_in[2];
    float* out = (float*)d_out;

    int nbatch = in_sizes[2];
    int ntime  = in_sizes[0] / nbatch;

    const int BLOCK = 256;
    int grid = (nbatch + BLOCK - 1) / BLOCK;
    bts_interp_kernel<<<grid, BLOCK, 0, stream>>>(times, values, t, out, ntime, nbatch);
}